// Round 1
// baseline (391.512 us; speedup 1.0000x reference)
//
#include <hip/hip_runtime.h>
#include <hip/hip_bf16.h>

// Bahdanau attention, fused:
//   q = dh @ Wq^T                         [32,1024]   (f32, exact, tiny)
//   scores[b,s] = v . tanh(q[b] + Wk @ enc[b,s])      (bf16 MFMA GEMM, fused epilogue)
//   attn = softmax(mask ? scores : -1e9)  [32,2048]
//   ctx[b,e] = sum_s attn[b,s]*enc[b,s,e] [32,1024]   (memory-bound pass)

#define NB 32
#define SS 2048
#define HD 1024
#define HE 1024
#define MM (NB * SS)   // 65536 rows

typedef float f32x4 __attribute__((ext_vector_type(4)));
typedef short bf16x8 __attribute__((ext_vector_type(8)));

static __device__ __forceinline__ short f2bf(float f) {
    union { __hip_bfloat16 h; short s; } u;
    u.h = __float2bfloat16(f);   // RN-even; compiler can fuse pairs to v_cvt_pk_bf16_f32
    return u.s;
}

// ---------------- q = dh @ Wq^T : one wave per output column d ----------------
__global__ __launch_bounds__(256) void qproj_kernel(const float* __restrict__ dh,
                                                    const float* __restrict__ Wq,
                                                    float* __restrict__ q) {
    const int wid  = threadIdx.x >> 6;
    const int lane = threadIdx.x & 63;
    const int d    = blockIdx.x * 4 + wid;          // grid=256 -> d in [0,1024)
    const float* wrow = Wq + (long)d * HD + lane * 16;
    f32x4 w0 = *(const f32x4*)(wrow + 0);
    f32x4 w1 = *(const f32x4*)(wrow + 4);
    f32x4 w2 = *(const f32x4*)(wrow + 8);
    f32x4 w3 = *(const f32x4*)(wrow + 12);
    for (int b = 0; b < NB; ++b) {
        const float* drow = dh + b * HD + lane * 16;
        f32x4 d0 = *(const f32x4*)(drow + 0);
        f32x4 d1 = *(const f32x4*)(drow + 4);
        f32x4 d2 = *(const f32x4*)(drow + 8);
        f32x4 d3 = *(const f32x4*)(drow + 12);
        f32x4 s4 = w0 * d0 + w1 * d1 + w2 * d2 + w3 * d3;
        float dot = s4[0] + s4[1] + s4[2] + s4[3];
        #pragma unroll
        for (int off = 32; off > 0; off >>= 1)
            dot += __shfl_xor(dot, off, 64);
        if (lane == 0) q[b * HD + d] = dot;
    }
}

// ---------------- fused GEMM + tanh + v-dot -> partial scores ----------------
// M=65536 (b*s rows), N=1024 (d), K=1024 (e).  A=enc (f32, row-major [M][K]),
// B^T = Wk (f32, [N][K] row-major).  128x128 tile, BK=32, 4 waves (2x2 of 64x64),
// on-the-fly f32->bf16 conversion into padded LDS [128][40] (2-way banks only).
__global__ __launch_bounds__(256) void score_kernel(const float* __restrict__ enc,
                                                    const float* __restrict__ Wk,
                                                    const float* __restrict__ qv,
                                                    const float* __restrict__ ven,
                                                    float* __restrict__ sp) {
    __shared__ short As[128][40];
    __shared__ short Bs[128][40];

    // XCD-aware swizzle: 8 consecutive slots on one XCD share an M-tile (A reuse in L2)
    const int bid  = blockIdx.x;
    const int xcd  = bid & 7;
    const int slot = bid >> 3;                // [0,512)
    const int mt   = xcd * 64 + (slot >> 3);  // [0,512)
    const int nt   = slot & 7;                // [0,8)

    const int tid  = threadIdx.x;
    const int lane = tid & 63;
    const int wid  = tid >> 6;
    const int wr   = wid >> 1;                // wave row (0..1)
    const int wc   = wid & 1;                 // wave col (0..1)

    const long mbase = (long)mt * 128;
    const int  nbase = nt * 128;

    f32x4 acc[4][4];
    #pragma unroll
    for (int m = 0; m < 4; ++m)
        #pragma unroll
        for (int n = 0; n < 4; ++n)
            acc[m][n] = (f32x4){0.f, 0.f, 0.f, 0.f};

    // staging assignment: thread -> (row r, k-half h); 16 f32 each from A and B
    const int r = tid >> 1;
    const int h = tid & 1;
    const float* asrc = enc + (mbase + r) * (long)HE + h * 16;
    const float* bsrc = Wk + (nbase + r) * (long)HE + h * 16;
    short* adst = &As[r][h * 16];
    short* bdst = &Bs[r][h * 16];

    const int frow = lane & 15;
    const int koff = (lane >> 4) * 8;

    // prefetch K-tile 0 into registers
    f32x4 a0 = *(const f32x4*)(asrc + 0);
    f32x4 a1 = *(const f32x4*)(asrc + 4);
    f32x4 a2 = *(const f32x4*)(asrc + 8);
    f32x4 a3 = *(const f32x4*)(asrc + 12);
    f32x4 b0 = *(const f32x4*)(bsrc + 0);
    f32x4 b1 = *(const f32x4*)(bsrc + 4);
    f32x4 b2 = *(const f32x4*)(bsrc + 8);
    f32x4 b3 = *(const f32x4*)(bsrc + 12);

    for (int kt = 0; kt < HE / 32; ++kt) {
        // pack current tile to bf16 and write LDS
        bf16x8 pa0, pa1, pb0, pb1;
        pa0[0]=f2bf(a0[0]); pa0[1]=f2bf(a0[1]); pa0[2]=f2bf(a0[2]); pa0[3]=f2bf(a0[3]);
        pa0[4]=f2bf(a1[0]); pa0[5]=f2bf(a1[1]); pa0[6]=f2bf(a1[2]); pa0[7]=f2bf(a1[3]);
        pa1[0]=f2bf(a2[0]); pa1[1]=f2bf(a2[1]); pa1[2]=f2bf(a2[2]); pa1[3]=f2bf(a2[3]);
        pa1[4]=f2bf(a3[0]); pa1[5]=f2bf(a3[1]); pa1[6]=f2bf(a3[2]); pa1[7]=f2bf(a3[3]);
        pb0[0]=f2bf(b0[0]); pb0[1]=f2bf(b0[1]); pb0[2]=f2bf(b0[2]); pb0[3]=f2bf(b0[3]);
        pb0[4]=f2bf(b1[0]); pb0[5]=f2bf(b1[1]); pb0[6]=f2bf(b1[2]); pb0[7]=f2bf(b1[3]);
        pb1[0]=f2bf(b2[0]); pb1[1]=f2bf(b2[1]); pb1[2]=f2bf(b2[2]); pb1[3]=f2bf(b2[3]);
        pb1[4]=f2bf(b3[0]); pb1[5]=f2bf(b3[1]); pb1[6]=f2bf(b3[2]); pb1[7]=f2bf(b3[3]);
        *(bf16x8*)(adst)     = pa0;
        *(bf16x8*)(adst + 8) = pa1;
        *(bf16x8*)(bdst)     = pb0;
        *(bf16x8*)(bdst + 8) = pb1;

        // issue next tile's global loads (latency hides under barrier+MFMA)
        if (kt + 1 < HE / 32) {
            asrc += 32; bsrc += 32;
            a0 = *(const f32x4*)(asrc + 0);
            a1 = *(const f32x4*)(asrc + 4);
            a2 = *(const f32x4*)(asrc + 8);
            a3 = *(const f32x4*)(asrc + 12);
            b0 = *(const f32x4*)(bsrc + 0);
            b1 = *(const f32x4*)(bsrc + 4);
            b2 = *(const f32x4*)(bsrc + 8);
            b3 = *(const f32x4*)(bsrc + 12);
        }
        __syncthreads();

        bf16x8 af[4], bfr[4];
        #pragma unroll
        for (int m = 0; m < 4; ++m)
            af[m] = *(const bf16x8*)&As[wr * 64 + m * 16 + frow][koff];
        #pragma unroll
        for (int n = 0; n < 4; ++n)
            bfr[n] = *(const bf16x8*)&Bs[wc * 64 + n * 16 + frow][koff];
        #pragma unroll
        for (int m = 0; m < 4; ++m)
            #pragma unroll
            for (int n = 0; n < 4; ++n)
                acc[m][n] = __builtin_amdgcn_mfma_f32_16x16x32_bf16(af[m], bfr[n], acc[m][n], 0, 0, 0);
        __syncthreads();
    }

    // epilogue: partial score = sum over this tile's 64 cols of v[c]*tanh(q[b,c]+k)
    // C/D layout (verified): col = lane&15, row = (lane>>4)*4 + reg
    const int bb = (int)(mbase >> 11);   // batch index (BM=128 divides S=2048)
    float qq[4], vv[4];
    #pragma unroll
    for (int n = 0; n < 4; ++n) {
        const int c = nbase + wc * 64 + n * 16 + frow;
        qq[n] = qv[bb * HD + c];
        vv[n] = ven[c];
    }
    float p[4][4];
    #pragma unroll
    for (int m = 0; m < 4; ++m) {
        #pragma unroll
        for (int rg = 0; rg < 4; ++rg) {
            float s = 0.f;
            #pragma unroll
            for (int n = 0; n < 4; ++n) {
                const float x = acc[m][n][rg] + qq[n];
                const float e = __expf(2.f * x);                     // inf/0 limits give t=+-1
                const float t = 1.f - 2.f * __builtin_amdgcn_rcpf(e + 1.f);
                s += vv[n] * t;
            }
            #pragma unroll
            for (int msk = 1; msk <= 8; msk <<= 1)
                s += __shfl_xor(s, msk, 64);    // reduce over the 16-lane col group
            p[m][rg] = s;
        }
    }
    if ((lane & 15) == 0) {
        const int g = lane >> 4;
        const long rowbase = mbase + wr * 64;
        float* dst = sp + (long)(nt * 2 + wc) * MM;   // 16 deterministic partial slots
        #pragma unroll
        for (int m = 0; m < 4; ++m)
            #pragma unroll
            for (int rg = 0; rg < 4; ++rg)
                dst[rowbase + m * 16 + g * 4 + rg] = p[m][rg];
    }
}

// ---------------- mask + softmax over S per batch ----------------
__global__ __launch_bounds__(256) void softmax_kernel(const float* __restrict__ sp,
                                                      const int* __restrict__ mask,
                                                      float* __restrict__ attn) {
    const int b = blockIdx.x;
    const int tid = threadIdx.x;
    const int lane = tid & 63;
    const int wid = tid >> 6;
    __shared__ float red[4];
    float sc[8];
    float mx = -3.0e38f;
    #pragma unroll
    for (int i = 0; i < 8; ++i) {
        const int s = tid + i * 256;
        float v = 0.f;
        #pragma unroll
        for (int k = 0; k < 16; ++k)
            v += sp[(long)k * MM + b * SS + s];
        if (mask[b * SS + s] == 0) v = -1e9f;
        sc[i] = v;
        mx = fmaxf(mx, v);
    }
    #pragma unroll
    for (int off = 32; off > 0; off >>= 1)
        mx = fmaxf(mx, __shfl_xor(mx, off, 64));
    if (lane == 0) red[wid] = mx;
    __syncthreads();
    mx = fmaxf(fmaxf(red[0], red[1]), fmaxf(red[2], red[3]));
    __syncthreads();
    float sum = 0.f;
    #pragma unroll
    for (int i = 0; i < 8; ++i) {
        const float e = __expf(sc[i] - mx);
        sc[i] = e;
        sum += e;
    }
    #pragma unroll
    for (int off = 32; off > 0; off >>= 1)
        sum += __shfl_xor(sum, off, 64);
    if (lane == 0) red[wid] = sum;
    __syncthreads();
    sum = red[0] + red[1] + red[2] + red[3];
    const float inv = 1.f / sum;
    #pragma unroll
    for (int i = 0; i < 8; ++i)
        attn[b * SS + tid + i * 256] = sc[i] * inv;
}

// ---------------- context: partial weighted sums over s-chunks ----------------
__global__ __launch_bounds__(256) void ctx_partial_kernel(const float* __restrict__ enc,
                                                          const float* __restrict__ attn,
                                                          float* __restrict__ cp) {
    const int b = blockIdx.x >> 5;        // 32 chunks per batch
    const int chunk = blockIdx.x & 31;
    const int tid = threadIdx.x;
    const float* ep = enc + ((long)b * SS + chunk * 64) * HE + tid * 4;
    const float* ap = attn + b * SS + chunk * 64;
    f32x4 acc = (f32x4){0.f, 0.f, 0.f, 0.f};
    #pragma unroll 4
    for (int s = 0; s < 64; ++s) {
        const float w = ap[s];
        const f32x4 v = *(const f32x4*)(ep + (long)s * HE);
        acc += w * v;
    }
    *(f32x4*)(cp + ((long)(b * 32 + chunk)) * HE + tid * 4) = acc;
}

__global__ __launch_bounds__(256) void ctx_reduce_kernel(const float* __restrict__ cp,
                                                         float* __restrict__ out) {
    const int o = blockIdx.x * 256 + threadIdx.x;   // [0, 32768)
    const int b = o >> 10;
    const int e = o & 1023;
    float s = 0.f;
    #pragma unroll
    for (int c = 0; c < 32; ++c)
        s += cp[((long)(b * 32 + c)) * HE + e];
    out[o] = s;
}

extern "C" void kernel_launch(void* const* d_in, const int* in_sizes, int n_in,
                              void* d_out, int out_size, void* d_ws, size_t ws_size,
                              hipStream_t stream) {
    const float* dh   = (const float*)d_in[0];   // [32,1024]
    const float* enc  = (const float*)d_in[1];   // [32,2048,1024]
    const int*   mask = (const int*)d_in[2];     // [32,2048]
    const float* Wq   = (const float*)d_in[3];   // [1024,1024]
    const float* Wk   = (const float*)d_in[4];   // [1024,1024]
    const float* Ve   = (const float*)d_in[5];   // [1,1024]

    float* out  = (float*)d_out;
    float* ctx  = out;               // [32,1024]
    float* attn = out + NB * HD;     // [32,2048]

    float* ws = (float*)d_ws;        // total 8.5 MB, every slot written before read
    float* wq_ = ws;                         // 32768 floats
    float* sp  = ws + 32768;                 // 16 * 65536 floats (score partials)
    float* cp  = sp + 16 * (long)MM;         // 32*32*1024 floats (context partials)

    qproj_kernel<<<256, 256, 0, stream>>>(dh, Wq, wq_);
    score_kernel<<<4096, 256, 0, stream>>>(enc, Wk, wq_, Ve, sp);
    softmax_kernel<<<32, 256, 0, stream>>>(sp, mask, attn);
    ctx_partial_kernel<<<1024, 256, 0, stream>>>(enc, attn, cp);
    ctx_reduce_kernel<<<128, 256, 0, stream>>>(cp, ctx);
}

// Round 2
// 347.940 us; speedup vs baseline: 1.1252x; 1.1252x over previous
//
#include <hip/hip_runtime.h>
#include <hip/hip_bf16.h>

// Bahdanau attention:
//   q = dh @ Wq^T                                    (f32, tiny)
//   enc,Wk -> bf16 pre-pass (one conversion per element)
//   scores[b,s] = v . tanh(q[b] + Wk @ enc[b,s])     (m97-style bf16 MFMA GEMM,
//                                                     global_load_lds staging, fused epilogue)
//   attn = softmax(mask ? scores : -1e9)
//   ctx[b,e] = sum_s attn[b,s]*enc[b,s,e]            (memory-bound pass, f32)

#define NB 32
#define SS 2048
#define HD 1024
#define HE 1024
#define MM (NB * SS)   // 65536 rows

typedef float f32x4 __attribute__((ext_vector_type(4)));
typedef short bf16x8 __attribute__((ext_vector_type(8)));

static __device__ __forceinline__ short f2bf(float f) {
    union { __hip_bfloat16 h; short s; } u;
    u.h = __float2bfloat16(f);
    return u.s;
}

// async global->LDS, 16B per lane; LDS dest = wave-uniform base + lane*16.
// generic->as1 is value-preserving; generic LDS ptr low 32 bits == LDS offset
// (flat->local addrspacecast is a truncate on amdgcn), so integer casts are safe.
static __device__ __forceinline__ void gload16(const void* g, const void* l) {
    __builtin_amdgcn_global_load_lds(
        (const __attribute__((address_space(1))) void*)(uintptr_t)(g),
        (__attribute__((address_space(3))) void*)(unsigned)(uintptr_t)(l),
        16, 0, 0);
}

// ---------------- f32 -> bf16 conversion pre-pass ----------------
__global__ __launch_bounds__(256) void cvt_bf16_kernel(const float* __restrict__ in,
                                                       short* __restrict__ out, int n8) {
    int i = blockIdx.x * 256 + threadIdx.x;
    const int stride = gridDim.x * 256;
    for (; i < n8; i += stride) {
        const f32x4 a = *(const f32x4*)(in + (long)i * 8);
        const f32x4 b = *(const f32x4*)(in + (long)i * 8 + 4);
        bf16x8 o;
        o[0] = f2bf(a[0]); o[1] = f2bf(a[1]); o[2] = f2bf(a[2]); o[3] = f2bf(a[3]);
        o[4] = f2bf(b[0]); o[5] = f2bf(b[1]); o[6] = f2bf(b[2]); o[7] = f2bf(b[3]);
        *(bf16x8*)(out + (long)i * 8) = o;
    }
}

// ---------------- q = dh @ Wq^T : one wave per output column d ----------------
__global__ __launch_bounds__(256) void qproj_kernel(const float* __restrict__ dh,
                                                    const float* __restrict__ Wq,
                                                    float* __restrict__ q) {
    const int wid  = threadIdx.x >> 6;
    const int lane = threadIdx.x & 63;
    const int d    = blockIdx.x * 4 + wid;
    const float* wrow = Wq + (long)d * HD + lane * 16;
    f32x4 w0 = *(const f32x4*)(wrow + 0);
    f32x4 w1 = *(const f32x4*)(wrow + 4);
    f32x4 w2 = *(const f32x4*)(wrow + 8);
    f32x4 w3 = *(const f32x4*)(wrow + 12);
    for (int b = 0; b < NB; ++b) {
        const float* drow = dh + b * HD + lane * 16;
        f32x4 d0 = *(const f32x4*)(drow + 0);
        f32x4 d1 = *(const f32x4*)(drow + 4);
        f32x4 d2 = *(const f32x4*)(drow + 8);
        f32x4 d3 = *(const f32x4*)(drow + 12);
        f32x4 s4 = w0 * d0 + w1 * d1 + w2 * d2 + w3 * d3;
        float dot = s4[0] + s4[1] + s4[2] + s4[3];
        #pragma unroll
        for (int off = 32; off > 0; off >>= 1)
            dot += __shfl_xor(dot, off, 64);
        if (lane == 0) q[b * HD + d] = dot;
    }
}

// ---------------- m97-style bf16 GEMM + fused tanh/v-dot epilogue ----------------
// M=65536, N=1024, K=1024. A=encb [M][1024] bf16 row-major, B^T=wkb [N][1024].
// 128x128 tile, BK=32, 4 waves (2x2 of 64x64), global_load_lds width-16,
// linear LDS [128][32] (swizzle is null at 128^2 + 2-phase per regime gate).
__global__ __launch_bounds__(256) void score_bf16_kernel(const short* __restrict__ encb,
                                                         const short* __restrict__ wkb,
                                                         const float* __restrict__ qv,
                                                         const float* __restrict__ ven,
                                                         float* __restrict__ sp) {
    __shared__ short As[4096];   // [128][32] bf16, 8 KB
    __shared__ short Bs[4096];

    // XCD-aware swizzle: 8 consecutive slots on one XCD share an M-tile (A L2 reuse)
    const int bid  = blockIdx.x;
    const int xcd  = bid & 7;
    const int slot = bid >> 3;
    const int mt   = xcd * 64 + (slot >> 3);   // [0,512)
    const int nt   = slot & 7;                 // [0,8)

    const int tid  = threadIdx.x;
    const int lane = tid & 63;
    const int wid  = tid >> 6;
    const int wr   = wid >> 1;
    const int wc   = wid & 1;

    const long mbase = (long)mt * 128;
    const int  nbase = nt * 128;

    f32x4 acc[4][4];
    #pragma unroll
    for (int m = 0; m < 4; ++m)
        #pragma unroll
        for (int n = 0; n < 4; ++n)
            acc[m][n] = (f32x4){0.f, 0.f, 0.f, 0.f};

    // staging map: flat 16B chunk c = j*256 + tid -> row c/4, col (c%4)*8 el
    const short* ag0 = encb + (mbase + (tid >> 2)) * (long)HE + (tid & 3) * 8;
    const short* ag1 = ag0 + 64 * (long)HE;
    const short* bg0 = wkb + ((long)(nbase + (tid >> 2))) * HE + (tid & 3) * 8;
    const short* bg1 = bg0 + 64 * (long)HE;

    short* adst0 = As + wid * 512;          // wave-uniform LDS bases (bytes: wid*1024)
    short* adst1 = As + 2048 + wid * 512;
    short* bdst0 = Bs + wid * 512;
    short* bdst1 = Bs + 2048 + wid * 512;

    const int frow = lane & 15;
    const int kby  = (lane >> 4) * 16;      // k-half byte offset within row

    for (int kt = 0; kt < HE / 32; ++kt) {
        gload16(ag0, adst0);
        gload16(ag1, adst1);
        gload16(bg0, bdst0);
        gload16(bg1, bdst1);
        ag0 += 32; ag1 += 32; bg0 += 32; bg1 += 32;
        __syncthreads();   // drains vmcnt (gload_lds done) + joins waves

        bf16x8 af[4], bfr[4];
        #pragma unroll
        for (int m = 0; m < 4; ++m)
            af[m] = *(const bf16x8*)((const char*)As + (wr * 64 + m * 16 + frow) * 64 + kby);
        #pragma unroll
        for (int n = 0; n < 4; ++n)
            bfr[n] = *(const bf16x8*)((const char*)Bs + (wc * 64 + n * 16 + frow) * 64 + kby);
        #pragma unroll
        for (int m = 0; m < 4; ++m)
            #pragma unroll
            for (int n = 0; n < 4; ++n)
                acc[m][n] = __builtin_amdgcn_mfma_f32_16x16x32_bf16(af[m], bfr[n], acc[m][n], 0, 0, 0);
        __syncthreads();   // LDS reads done before next iter overwrites
    }

    // epilogue: partial score = sum over this tile's 64 cols of v[c]*tanh(q[b,c]+k)
    // C/D layout: col = lane&15, row = (lane>>4)*4 + reg
    const int bb = (int)(mbase >> 11);
    float qq[4], vv[4];
    #pragma unroll
    for (int n = 0; n < 4; ++n) {
        const int c = nbase + wc * 64 + n * 16 + frow;
        qq[n] = qv[bb * HD + c];
        vv[n] = ven[c];
    }
    float p[4][4];
    #pragma unroll
    for (int m = 0; m < 4; ++m) {
        #pragma unroll
        for (int rg = 0; rg < 4; ++rg) {
            float s = 0.f;
            #pragma unroll
            for (int n = 0; n < 4; ++n) {
                const float x = acc[m][n][rg] + qq[n];
                const float e = __expf(2.f * x);
                const float t = 1.f - 2.f * __builtin_amdgcn_rcpf(e + 1.f);
                s += vv[n] * t;
            }
            #pragma unroll
            for (int msk = 1; msk <= 8; msk <<= 1)
                s += __shfl_xor(s, msk, 64);
            p[m][rg] = s;
        }
    }
    if ((lane & 15) == 0) {
        const int g = lane >> 4;
        const long rowbase = mbase + wr * 64;
        float* dst = sp + (long)(nt * 2 + wc) * MM;
        #pragma unroll
        for (int m = 0; m < 4; ++m)
            #pragma unroll
            for (int rg = 0; rg < 4; ++rg)
                dst[rowbase + m * 16 + g * 4 + rg] = p[m][rg];
    }
}

// ---------------- fallback (ws too small): in-loop-convert GEMM ----------------
__global__ __launch_bounds__(256) void score_f32_kernel(const float* __restrict__ enc,
                                                        const float* __restrict__ Wk,
                                                        const float* __restrict__ qv,
                                                        const float* __restrict__ ven,
                                                        float* __restrict__ sp) {
    __shared__ short As[128][40];
    __shared__ short Bs[128][40];
    const int bid  = blockIdx.x;
    const int xcd  = bid & 7;
    const int slot = bid >> 3;
    const int mt   = xcd * 64 + (slot >> 3);
    const int nt   = slot & 7;
    const int tid  = threadIdx.x;
    const int lane = tid & 63;
    const int wid  = tid >> 6;
    const int wr   = wid >> 1;
    const int wc   = wid & 1;
    const long mbase = (long)mt * 128;
    const int  nbase = nt * 128;
    f32x4 acc[4][4];
    #pragma unroll
    for (int m = 0; m < 4; ++m)
        #pragma unroll
        for (int n = 0; n < 4; ++n)
            acc[m][n] = (f32x4){0.f, 0.f, 0.f, 0.f};
    const int r = tid >> 1;
    const int h = tid & 1;
    const float* asrc = enc + (mbase + r) * (long)HE + h * 16;
    const float* bsrc = Wk + (nbase + r) * (long)HE + h * 16;
    short* adst = &As[r][h * 16];
    short* bdst = &Bs[r][h * 16];
    const int frow = lane & 15;
    const int koff = (lane >> 4) * 8;
    f32x4 a0 = *(const f32x4*)(asrc + 0), a1 = *(const f32x4*)(asrc + 4);
    f32x4 a2 = *(const f32x4*)(asrc + 8), a3 = *(const f32x4*)(asrc + 12);
    f32x4 b0 = *(const f32x4*)(bsrc + 0), b1 = *(const f32x4*)(bsrc + 4);
    f32x4 b2 = *(const f32x4*)(bsrc + 8), b3 = *(const f32x4*)(bsrc + 12);
    for (int kt = 0; kt < HE / 32; ++kt) {
        bf16x8 pa0, pa1, pb0, pb1;
        pa0[0]=f2bf(a0[0]); pa0[1]=f2bf(a0[1]); pa0[2]=f2bf(a0[2]); pa0[3]=f2bf(a0[3]);
        pa0[4]=f2bf(a1[0]); pa0[5]=f2bf(a1[1]); pa0[6]=f2bf(a1[2]); pa0[7]=f2bf(a1[3]);
        pa1[0]=f2bf(a2[0]); pa1[1]=f2bf(a2[1]); pa1[2]=f2bf(a2[2]); pa1[3]=f2bf(a2[3]);
        pa1[4]=f2bf(a3[0]); pa1[5]=f2bf(a3[1]); pa1[6]=f2bf(a3[2]); pa1[7]=f2bf(a3[3]);
        pb0[0]=f2bf(b0[0]); pb0[1]=f2bf(b0[1]); pb0[2]=f2bf(b0[2]); pb0[3]=f2bf(b0[3]);
        pb0[4]=f2bf(b1[0]); pb0[5]=f2bf(b1[1]); pb0[6]=f2bf(b1[2]); pb0[7]=f2bf(b1[3]);
        pb1[0]=f2bf(b2[0]); pb1[1]=f2bf(b2[1]); pb1[2]=f2bf(b2[2]); pb1[3]=f2bf(b2[3]);
        pb1[4]=f2bf(b3[0]); pb1[5]=f2bf(b3[1]); pb1[6]=f2bf(b3[2]); pb1[7]=f2bf(b3[3]);
        *(bf16x8*)(adst)     = pa0;
        *(bf16x8*)(adst + 8) = pa1;
        *(bf16x8*)(bdst)     = pb0;
        *(bf16x8*)(bdst + 8) = pb1;
        if (kt + 1 < HE / 32) {
            asrc += 32; bsrc += 32;
            a0 = *(const f32x4*)(asrc + 0); a1 = *(const f32x4*)(asrc + 4);
            a2 = *(const f32x4*)(asrc + 8); a3 = *(const f32x4*)(asrc + 12);
            b0 = *(const f32x4*)(bsrc + 0); b1 = *(const f32x4*)(bsrc + 4);
            b2 = *(const f32x4*)(bsrc + 8); b3 = *(const f32x4*)(bsrc + 12);
        }
        __syncthreads();
        bf16x8 af[4], bfr[4];
        #pragma unroll
        for (int m = 0; m < 4; ++m)
            af[m] = *(const bf16x8*)&As[wr * 64 + m * 16 + frow][koff];
        #pragma unroll
        for (int n = 0; n < 4; ++n)
            bfr[n] = *(const bf16x8*)&Bs[wc * 64 + n * 16 + frow][koff];
        #pragma unroll
        for (int m = 0; m < 4; ++m)
            #pragma unroll
            for (int n = 0; n < 4; ++n)
                acc[m][n] = __builtin_amdgcn_mfma_f32_16x16x32_bf16(af[m], bfr[n], acc[m][n], 0, 0, 0);
        __syncthreads();
    }
    const int bb = (int)(mbase >> 11);
    float qq[4], vv[4];
    #pragma unroll
    for (int n = 0; n < 4; ++n) {
        const int c = nbase + wc * 64 + n * 16 + frow;
        qq[n] = qv[bb * HD + c];
        vv[n] = ven[c];
    }
    float p[4][4];
    #pragma unroll
    for (int m = 0; m < 4; ++m) {
        #pragma unroll
        for (int rg = 0; rg < 4; ++rg) {
            float s = 0.f;
            #pragma unroll
            for (int n = 0; n < 4; ++n) {
                const float x = acc[m][n][rg] + qq[n];
                const float e = __expf(2.f * x);
                const float t = 1.f - 2.f * __builtin_amdgcn_rcpf(e + 1.f);
                s += vv[n] * t;
            }
            #pragma unroll
            for (int msk = 1; msk <= 8; msk <<= 1)
                s += __shfl_xor(s, msk, 64);
            p[m][rg] = s;
        }
    }
    if ((lane & 15) == 0) {
        const int g = lane >> 4;
        const long rowbase = mbase + wr * 64;
        float* dst = sp + (long)(nt * 2 + wc) * MM;
        #pragma unroll
        for (int m = 0; m < 4; ++m)
            #pragma unroll
            for (int rg = 0; rg < 4; ++rg)
                dst[rowbase + m * 16 + g * 4 + rg] = p[m][rg];
    }
}

// ---------------- mask + softmax over S per batch ----------------
__global__ __launch_bounds__(256) void softmax_kernel(const float* __restrict__ sp,
                                                      const int* __restrict__ mask,
                                                      float* __restrict__ attn) {
    const int b = blockIdx.x;
    const int tid = threadIdx.x;
    const int lane = tid & 63;
    const int wid = tid >> 6;
    __shared__ float red[4];
    float sc[8];
    float mx = -3.0e38f;
    #pragma unroll
    for (int i = 0; i < 8; ++i) {
        const int s = tid + i * 256;
        float v = 0.f;
        #pragma unroll
        for (int k = 0; k < 16; ++k)
            v += sp[(long)k * MM + b * SS + s];
        if (mask[b * SS + s] == 0) v = -1e9f;
        sc[i] = v;
        mx = fmaxf(mx, v);
    }
    #pragma unroll
    for (int off = 32; off > 0; off >>= 1)
        mx = fmaxf(mx, __shfl_xor(mx, off, 64));
    if (lane == 0) red[wid] = mx;
    __syncthreads();
    mx = fmaxf(fmaxf(red[0], red[1]), fmaxf(red[2], red[3]));
    __syncthreads();
    float sum = 0.f;
    #pragma unroll
    for (int i = 0; i < 8; ++i) {
        const float e = __expf(sc[i] - mx);
        sc[i] = e;
        sum += e;
    }
    #pragma unroll
    for (int off = 32; off > 0; off >>= 1)
        sum += __shfl_xor(sum, off, 64);
    if (lane == 0) red[wid] = sum;
    __syncthreads();
    sum = red[0] + red[1] + red[2] + red[3];
    const float inv = 1.f / sum;
    #pragma unroll
    for (int i = 0; i < 8; ++i)
        attn[b * SS + tid + i * 256] = sc[i] * inv;
}

// ---------------- context: partial weighted sums over s-chunks ----------------
__global__ __launch_bounds__(256) void ctx_partial_kernel(const float* __restrict__ enc,
                                                          const float* __restrict__ attn,
                                                          float* __restrict__ cp) {
    const int b = blockIdx.x >> 5;
    const int chunk = blockIdx.x & 31;
    const int tid = threadIdx.x;
    const float* ep = enc + ((long)b * SS + chunk * 64) * HE + tid * 4;
    const float* ap = attn + b * SS + chunk * 64;
    f32x4 acc = (f32x4){0.f, 0.f, 0.f, 0.f};
    #pragma unroll 4
    for (int s = 0; s < 64; ++s) {
        const float w = ap[s];
        const f32x4 v = *(const f32x4*)(ep + (long)s * HE);
        acc += w * v;
    }
    *(f32x4*)(cp + ((long)(b * 32 + chunk)) * HE + tid * 4) = acc;
}

__global__ __launch_bounds__(256) void ctx_reduce_kernel(const float* __restrict__ cp,
                                                         float* __restrict__ out) {
    const int o = blockIdx.x * 256 + threadIdx.x;
    const int b = o >> 10;
    const int e = o & 1023;
    float s = 0.f;
    #pragma unroll
    for (int c = 0; c < 32; ++c)
        s += cp[((long)(b * 32 + c)) * HE + e];
    out[o] = s;
}

extern "C" void kernel_launch(void* const* d_in, const int* in_sizes, int n_in,
                              void* d_out, int out_size, void* d_ws, size_t ws_size,
                              hipStream_t stream) {
    const float* dh   = (const float*)d_in[0];
    const float* enc  = (const float*)d_in[1];
    const int*   mask = (const int*)d_in[2];
    const float* Wq   = (const float*)d_in[3];
    const float* Wk   = (const float*)d_in[4];
    const float* Ve   = (const float*)d_in[5];

    float* out  = (float*)d_out;
    float* ctx  = out;
    float* attn = out + NB * HD;

    float* ws  = (float*)d_ws;
    float* wq_ = ws;                          // 32768 f
    float* sp  = ws + 32768;                  // 16*65536 f
    float* cp  = sp + 16 * (long)MM;          // 32*32*1024 f
    short* wkb = (short*)(cp + 32 * 32 * HE); // 1M bf16   (2 MB)
    short* encb = wkb + (long)HD * HE;        // 67.1M bf16 (128 MB)
    const size_t need = (size_t)((char*)(encb + (long)MM * HE) - (char*)d_ws);

    qproj_kernel<<<256, 256, 0, stream>>>(dh, Wq, wq_);
    if (ws_size >= need) {
        cvt_bf16_kernel<<<512, 256, 0, stream>>>(Wk, wkb, HD * HE / 8);
        cvt_bf16_kernel<<<2048, 256, 0, stream>>>(enc, encb, (int)((long)MM * HE / 8));
        score_bf16_kernel<<<4096, 256, 0, stream>>>(encb, wkb, wq_, Ve, sp);
    } else {
        score_f32_kernel<<<4096, 256, 0, stream>>>(enc, Wk, wq_, Ve, sp);
    }
    softmax_kernel<<<32, 256, 0, stream>>>(sp, mask, attn);
    ctx_partial_kernel<<<1024, 256, 0, stream>>>(enc, attn, cp);
    ctx_reduce_kernel<<<128, 256, 0, stream>>>(cp, ctx);
}

// Round 3
// 339.968 us; speedup vs baseline: 1.1516x; 1.0234x over previous
//
#include <hip/hip_runtime.h>
#include <hip/hip_bf16.h>

// Bahdanau attention:
//   q = dh @ Wq^T                                    (f32, tiny)
//   enc,Wk -> bf16 pre-pass (one conversion per element)
//   scores[b,s] = v . tanh(q[b] + Wk @ enc[b,s])     (bf16 MFMA GEMM, 2-deep
//                      counted-vmcnt prefetch pipeline, global_load_lds staging)
//   attn = softmax(mask ? scores : -1e9)
//   ctx[b,e] = sum_s attn[b,s]*enc_bf16[b,s,e]       (memory-bound pass, bf16)

#define NB 32
#define SS 2048
#define HD 1024
#define HE 1024
#define MM (NB * SS)   // 65536 rows

typedef float f32x4 __attribute__((ext_vector_type(4)));
typedef short bf16x8 __attribute__((ext_vector_type(8)));
typedef short short4v __attribute__((ext_vector_type(4)));

static __device__ __forceinline__ short f2bf(float f) {
    union { __hip_bfloat16 h; short s; } u;
    u.h = __float2bfloat16(f);
    return u.s;
}
static __device__ __forceinline__ float bf2f(short s) {
    union { float f; unsigned u; } u;
    u.u = ((unsigned)(unsigned short)s) << 16;
    return u.f;
}

// async global->LDS, 16B per lane; LDS dest = wave-uniform base + lane*16.
static __device__ __forceinline__ void gload16(const void* g, const void* l) {
    __builtin_amdgcn_global_load_lds(
        (const __attribute__((address_space(1))) void*)(uintptr_t)(g),
        (__attribute__((address_space(3))) void*)(unsigned)(uintptr_t)(l),
        16, 0, 0);
}

// ---------------- f32 -> bf16 conversion pre-pass ----------------
__global__ __launch_bounds__(256) void cvt_bf16_kernel(const float* __restrict__ in,
                                                       short* __restrict__ out, int n8) {
    int i = blockIdx.x * 256 + threadIdx.x;
    const int stride = gridDim.x * 256;
    for (; i < n8; i += stride) {
        const f32x4 a = *(const f32x4*)(in + (long)i * 8);
        const f32x4 b = *(const f32x4*)(in + (long)i * 8 + 4);
        bf16x8 o;
        o[0] = f2bf(a[0]); o[1] = f2bf(a[1]); o[2] = f2bf(a[2]); o[3] = f2bf(a[3]);
        o[4] = f2bf(b[0]); o[5] = f2bf(b[1]); o[6] = f2bf(b[2]); o[7] = f2bf(b[3]);
        *(bf16x8*)(out + (long)i * 8) = o;
    }
}

// ---------------- q = dh @ Wq^T : one wave per output column d ----------------
__global__ __launch_bounds__(256) void qproj_kernel(const float* __restrict__ dh,
                                                    const float* __restrict__ Wq,
                                                    float* __restrict__ q) {
    const int wid  = threadIdx.x >> 6;
    const int lane = threadIdx.x & 63;
    const int d    = blockIdx.x * 4 + wid;
    const float* wrow = Wq + (long)d * HD + lane * 16;
    f32x4 w0 = *(const f32x4*)(wrow + 0);
    f32x4 w1 = *(const f32x4*)(wrow + 4);
    f32x4 w2 = *(const f32x4*)(wrow + 8);
    f32x4 w3 = *(const f32x4*)(wrow + 12);
    for (int b = 0; b < NB; ++b) {
        const float* drow = dh + b * HD + lane * 16;
        f32x4 d0 = *(const f32x4*)(drow + 0);
        f32x4 d1 = *(const f32x4*)(drow + 4);
        f32x4 d2 = *(const f32x4*)(drow + 8);
        f32x4 d3 = *(const f32x4*)(drow + 12);
        f32x4 s4 = w0 * d0 + w1 * d1 + w2 * d2 + w3 * d3;
        float dot = s4[0] + s4[1] + s4[2] + s4[3];
        #pragma unroll
        for (int off = 32; off > 0; off >>= 1)
            dot += __shfl_xor(dot, off, 64);
        if (lane == 0) q[b * HD + d] = dot;
    }
}

// ---------------- bf16 GEMM + fused tanh/v-dot epilogue ----------------
// M=65536, N=1024, K=1024. A=encb [M][1024] bf16 row-major, B^T=wkb [N][1024].
// 128x128 tile, BK=32, 4 waves (2x2 of 64x64), global_load_lds width-16,
// triple-buffered LDS, 2-deep prefetch, counted vmcnt(4) (T3-min + T4).
__global__ __launch_bounds__(256) void score_bf16_kernel(const short* __restrict__ encb,
                                                         const short* __restrict__ wkb,
                                                         const float* __restrict__ qv,
                                                         const float* __restrict__ ven,
                                                         float* __restrict__ sp) {
    __shared__ short As[3][4096];   // 3 x [128][32] bf16, 8 KB each
    __shared__ short Bs[3][4096];

    // XCD-aware swizzle: 8 consecutive slots on one XCD share an M-tile (A L2 reuse)
    const int bid  = blockIdx.x;
    const int xcd  = bid & 7;
    const int slot = bid >> 3;
    const int mt   = xcd * 64 + (slot >> 3);   // [0,512)
    const int nt   = slot & 7;                 // [0,8)

    const int tid  = threadIdx.x;
    const int lane = tid & 63;
    const int wid  = tid >> 6;
    const int wr   = wid >> 1;
    const int wc   = wid & 1;

    const long mbase = (long)mt * 128;
    const int  nbase = nt * 128;

    f32x4 acc[4][4];
    #pragma unroll
    for (int m = 0; m < 4; ++m)
        #pragma unroll
        for (int n = 0; n < 4; ++n)
            acc[m][n] = (f32x4){0.f, 0.f, 0.f, 0.f};

    // staging map: flat 16B chunk c = tid -> row c/4, col (c%4)*8 el (two row-halves)
    const short* ag0 = encb + (mbase + (tid >> 2)) * (long)HE + (tid & 3) * 8;
    const short* ag1 = ag0 + 64 * (long)HE;
    const short* bg0 = wkb + ((long)(nbase + (tid >> 2))) * HE + (tid & 3) * 8;
    const short* bg1 = bg0 + 64 * (long)HE;

    const int frow = lane & 15;
    const int kby  = (lane >> 4) * 16;      // k-half byte offset within row

    #define STAGE(buf, kt)                                        \
        do {                                                      \
            const int ko = (kt) * 32;                             \
            gload16(ag0 + ko, &As[buf][0]    + wid * 512);        \
            gload16(ag1 + ko, &As[buf][2048] + wid * 512);        \
            gload16(bg0 + ko, &Bs[buf][0]    + wid * 512);        \
            gload16(bg1 + ko, &Bs[buf][2048] + wid * 512);        \
        } while (0)

    // prologue: 2-deep prefetch; vmcnt(4) -> tile 0 landed for all waves
    STAGE(0, 0);
    STAGE(1, 1);
    asm volatile("s_waitcnt vmcnt(4)\n\ts_barrier" ::: "memory");

    for (int kt = 0; kt < HE / 32; ++kt) {
        const int cur = kt % 3;
        if (kt + 2 < HE / 32) STAGE((kt + 2) % 3, kt + 2);

        bf16x8 af[4], bfr[4];
        #pragma unroll
        for (int m = 0; m < 4; ++m)
            af[m] = *(const bf16x8*)((const char*)As[cur] + (wr * 64 + m * 16 + frow) * 64 + kby);
        #pragma unroll
        for (int n = 0; n < 4; ++n)
            bfr[n] = *(const bf16x8*)((const char*)Bs[cur] + (wc * 64 + n * 16 + frow) * 64 + kby);
        #pragma unroll
        for (int m = 0; m < 4; ++m)
            #pragma unroll
            for (int n = 0; n < 4; ++n)
                acc[m][n] = __builtin_amdgcn_mfma_f32_16x16x32_bf16(af[m], bfr[n], acc[m][n], 0, 0, 0);

        // fused wait+barrier (single asm so no ds_read can slip between them):
        // vmcnt(4) leaves tile kt+2's 4 loads in flight, guarantees kt+1 landed.
        if (kt < HE / 32 - 2)      asm volatile("s_waitcnt vmcnt(4)\n\ts_barrier" ::: "memory");
        else if (kt < HE / 32 - 1) asm volatile("s_waitcnt vmcnt(0)\n\ts_barrier" ::: "memory");
    }
    #undef STAGE

    // epilogue: partial score = sum over this tile's 64 cols of v[c]*tanh(q[b,c]+k)
    // C/D layout: col = lane&15, row = (lane>>4)*4 + reg
    const int bb = (int)(mbase >> 11);
    float qq[4], vv[4];
    #pragma unroll
    for (int n = 0; n < 4; ++n) {
        const int c = nbase + wc * 64 + n * 16 + frow;
        qq[n] = qv[bb * HD + c];
        vv[n] = ven[c];
    }
    float p[4][4];
    #pragma unroll
    for (int m = 0; m < 4; ++m) {
        #pragma unroll
        for (int rg = 0; rg < 4; ++rg) {
            float s = 0.f;
            #pragma unroll
            for (int n = 0; n < 4; ++n) {
                const float x = acc[m][n][rg] + qq[n];
                const float e = __expf(2.f * x);
                const float t = 1.f - 2.f * __builtin_amdgcn_rcpf(e + 1.f);
                s += vv[n] * t;
            }
            #pragma unroll
            for (int msk = 1; msk <= 8; msk <<= 1)
                s += __shfl_xor(s, msk, 64);
            p[m][rg] = s;
        }
    }
    if ((lane & 15) == 0) {
        const int g = lane >> 4;
        const long rowbase = mbase + wr * 64;
        float* dst = sp + (long)(nt * 2 + wc) * MM;
        #pragma unroll
        for (int m = 0; m < 4; ++m)
            #pragma unroll
            for (int rg = 0; rg < 4; ++rg)
                dst[rowbase + m * 16 + g * 4 + rg] = p[m][rg];
    }
}

// ---------------- fallback (ws too small): in-loop-convert GEMM ----------------
__global__ __launch_bounds__(256) void score_f32_kernel(const float* __restrict__ enc,
                                                        const float* __restrict__ Wk,
                                                        const float* __restrict__ qv,
                                                        const float* __restrict__ ven,
                                                        float* __restrict__ sp) {
    __shared__ short As[128][40];
    __shared__ short Bs[128][40];
    const int bid  = blockIdx.x;
    const int xcd  = bid & 7;
    const int slot = bid >> 3;
    const int mt   = xcd * 64 + (slot >> 3);
    const int nt   = slot & 7;
    const int tid  = threadIdx.x;
    const int lane = tid & 63;
    const int wid  = tid >> 6;
    const int wr   = wid >> 1;
    const int wc   = wid & 1;
    const long mbase = (long)mt * 128;
    const int  nbase = nt * 128;
    f32x4 acc[4][4];
    #pragma unroll
    for (int m = 0; m < 4; ++m)
        #pragma unroll
        for (int n = 0; n < 4; ++n)
            acc[m][n] = (f32x4){0.f, 0.f, 0.f, 0.f};
    const int r = tid >> 1;
    const int h = tid & 1;
    const float* asrc = enc + (mbase + r) * (long)HE + h * 16;
    const float* bsrc = Wk + (nbase + r) * (long)HE + h * 16;
    short* adst = &As[r][h * 16];
    short* bdst = &Bs[r][h * 16];
    const int frow = lane & 15;
    const int koff = (lane >> 4) * 8;
    f32x4 a0 = *(const f32x4*)(asrc + 0), a1 = *(const f32x4*)(asrc + 4);
    f32x4 a2 = *(const f32x4*)(asrc + 8), a3 = *(const f32x4*)(asrc + 12);
    f32x4 b0 = *(const f32x4*)(bsrc + 0), b1 = *(const f32x4*)(bsrc + 4);
    f32x4 b2 = *(const f32x4*)(bsrc + 8), b3 = *(const f32x4*)(bsrc + 12);
    for (int kt = 0; kt < HE / 32; ++kt) {
        bf16x8 pa0, pa1, pb0, pb1;
        pa0[0]=f2bf(a0[0]); pa0[1]=f2bf(a0[1]); pa0[2]=f2bf(a0[2]); pa0[3]=f2bf(a0[3]);
        pa0[4]=f2bf(a1[0]); pa0[5]=f2bf(a1[1]); pa0[6]=f2bf(a1[2]); pa0[7]=f2bf(a1[3]);
        pa1[0]=f2bf(a2[0]); pa1[1]=f2bf(a2[1]); pa1[2]=f2bf(a2[2]); pa1[3]=f2bf(a2[3]);
        pa1[4]=f2bf(a3[0]); pa1[5]=f2bf(a3[1]); pa1[6]=f2bf(a3[2]); pa1[7]=f2bf(a3[3]);
        pb0[0]=f2bf(b0[0]); pb0[1]=f2bf(b0[1]); pb0[2]=f2bf(b0[2]); pb0[3]=f2bf(b0[3]);
        pb0[4]=f2bf(b1[0]); pb0[5]=f2bf(b1[1]); pb0[6]=f2bf(b1[2]); pb0[7]=f2bf(b1[3]);
        pb1[0]=f2bf(b2[0]); pb1[1]=f2bf(b2[1]); pb1[2]=f2bf(b2[2]); pb1[3]=f2bf(b2[3]);
        pb1[4]=f2bf(b3[0]); pb1[5]=f2bf(b3[1]); pb1[6]=f2bf(b3[2]); pb1[7]=f2bf(b3[3]);
        *(bf16x8*)(adst)     = pa0;
        *(bf16x8*)(adst + 8) = pa1;
        *(bf16x8*)(bdst)     = pb0;
        *(bf16x8*)(bdst + 8) = pb1;
        if (kt + 1 < HE / 32) {
            asrc += 32; bsrc += 32;
            a0 = *(const f32x4*)(asrc + 0); a1 = *(const f32x4*)(asrc + 4);
            a2 = *(const f32x4*)(asrc + 8); a3 = *(const f32x4*)(asrc + 12);
            b0 = *(const f32x4*)(bsrc + 0); b1 = *(const f32x4*)(bsrc + 4);
            b2 = *(const f32x4*)(bsrc + 8); b3 = *(const f32x4*)(bsrc + 12);
        }
        __syncthreads();
        bf16x8 af[4], bfr[4];
        #pragma unroll
        for (int m = 0; m < 4; ++m)
            af[m] = *(const bf16x8*)&As[wr * 64 + m * 16 + frow][koff];
        #pragma unroll
        for (int n = 0; n < 4; ++n)
            bfr[n] = *(const bf16x8*)&Bs[wc * 64 + n * 16 + frow][koff];
        #pragma unroll
        for (int m = 0; m < 4; ++m)
            #pragma unroll
            for (int n = 0; n < 4; ++n)
                acc[m][n] = __builtin_amdgcn_mfma_f32_16x16x32_bf16(af[m], bfr[n], acc[m][n], 0, 0, 0);
        __syncthreads();
    }
    const int bb = (int)(mbase >> 11);
    float qq[4], vv[4];
    #pragma unroll
    for (int n = 0; n < 4; ++n) {
        const int c = nbase + wc * 64 + n * 16 + frow;
        qq[n] = qv[bb * HD + c];
        vv[n] = ven[c];
    }
    float p[4][4];
    #pragma unroll
    for (int m = 0; m < 4; ++m) {
        #pragma unroll
        for (int rg = 0; rg < 4; ++rg) {
            float s = 0.f;
            #pragma unroll
            for (int n = 0; n < 4; ++n) {
                const float x = acc[m][n][rg] + qq[n];
                const float e = __expf(2.f * x);
                const float t = 1.f - 2.f * __builtin_amdgcn_rcpf(e + 1.f);
                s += vv[n] * t;
            }
            #pragma unroll
            for (int msk = 1; msk <= 8; msk <<= 1)
                s += __shfl_xor(s, msk, 64);
            p[m][rg] = s;
        }
    }
    if ((lane & 15) == 0) {
        const int g = lane >> 4;
        const long rowbase = mbase + wr * 64;
        float* dst = sp + (long)(nt * 2 + wc) * MM;
        #pragma unroll
        for (int m = 0; m < 4; ++m)
            #pragma unroll
            for (int rg = 0; rg < 4; ++rg)
                dst[rowbase + m * 16 + g * 4 + rg] = p[m][rg];
    }
}

// ---------------- mask + softmax over S per batch ----------------
__global__ __launch_bounds__(256) void softmax_kernel(const float* __restrict__ sp,
                                                      const int* __restrict__ mask,
                                                      float* __restrict__ attn) {
    const int b = blockIdx.x;
    const int tid = threadIdx.x;
    const int lane = tid & 63;
    const int wid = tid >> 6;
    __shared__ float red[4];
    float sc[8];
    float mx = -3.0e38f;
    #pragma unroll
    for (int i = 0; i < 8; ++i) {
        const int s = tid + i * 256;
        float v = 0.f;
        #pragma unroll
        for (int k = 0; k < 16; ++k)
            v += sp[(long)k * MM + b * SS + s];
        if (mask[b * SS + s] == 0) v = -1e9f;
        sc[i] = v;
        mx = fmaxf(mx, v);
    }
    #pragma unroll
    for (int off = 32; off > 0; off >>= 1)
        mx = fmaxf(mx, __shfl_xor(mx, off, 64));
    if (lane == 0) red[wid] = mx;
    __syncthreads();
    mx = fmaxf(fmaxf(red[0], red[1]), fmaxf(red[2], red[3]));
    __syncthreads();
    float sum = 0.f;
    #pragma unroll
    for (int i = 0; i < 8; ++i) {
        const float e = __expf(sc[i] - mx);
        sc[i] = e;
        sum += e;
    }
    #pragma unroll
    for (int off = 32; off > 0; off >>= 1)
        sum += __shfl_xor(sum, off, 64);
    if (lane == 0) red[wid] = sum;
    __syncthreads();
    sum = red[0] + red[1] + red[2] + red[3];
    const float inv = 1.f / sum;
    #pragma unroll
    for (int i = 0; i < 8; ++i)
        attn[b * SS + tid + i * 256] = sc[i] * inv;
}

// ---------------- context: partial weighted sums over s-chunks (bf16 enc) ----------------
__global__ __launch_bounds__(256) void ctx_partial_bf16_kernel(const short* __restrict__ encb,
                                                               const float* __restrict__ attn,
                                                               float* __restrict__ cp) {
    const int b = blockIdx.x >> 5;
    const int chunk = blockIdx.x & 31;
    const int tid = threadIdx.x;
    const short* ep = encb + ((long)b * SS + chunk * 64) * HE + tid * 4;
    const float* ap = attn + b * SS + chunk * 64;
    f32x4 acc = (f32x4){0.f, 0.f, 0.f, 0.f};
    #pragma unroll 4
    for (int s = 0; s < 64; ++s) {
        const float w = ap[s];
        const short4v v = *(const short4v*)(ep + (long)s * HE);
        acc[0] += w * bf2f(v[0]);
        acc[1] += w * bf2f(v[1]);
        acc[2] += w * bf2f(v[2]);
        acc[3] += w * bf2f(v[3]);
    }
    *(f32x4*)(cp + ((long)(b * 32 + chunk)) * HE + tid * 4) = acc;
}

__global__ __launch_bounds__(256) void ctx_partial_f32_kernel(const float* __restrict__ enc,
                                                              const float* __restrict__ attn,
                                                              float* __restrict__ cp) {
    const int b = blockIdx.x >> 5;
    const int chunk = blockIdx.x & 31;
    const int tid = threadIdx.x;
    const float* ep = enc + ((long)b * SS + chunk * 64) * HE + tid * 4;
    const float* ap = attn + b * SS + chunk * 64;
    f32x4 acc = (f32x4){0.f, 0.f, 0.f, 0.f};
    #pragma unroll 4
    for (int s = 0; s < 64; ++s) {
        const float w = ap[s];
        const f32x4 v = *(const f32x4*)(ep + (long)s * HE);
        acc += w * v;
    }
    *(f32x4*)(cp + ((long)(b * 32 + chunk)) * HE + tid * 4) = acc;
}

__global__ __launch_bounds__(256) void ctx_reduce_kernel(const float* __restrict__ cp,
                                                         float* __restrict__ out) {
    const int o = blockIdx.x * 256 + threadIdx.x;
    const int b = o >> 10;
    const int e = o & 1023;
    float s = 0.f;
    #pragma unroll
    for (int c = 0; c < 32; ++c)
        s += cp[((long)(b * 32 + c)) * HE + e];
    out[o] = s;
}

extern "C" void kernel_launch(void* const* d_in, const int* in_sizes, int n_in,
                              void* d_out, int out_size, void* d_ws, size_t ws_size,
                              hipStream_t stream) {
    const float* dh   = (const float*)d_in[0];
    const float* enc  = (const float*)d_in[1];
    const int*   mask = (const int*)d_in[2];
    const float* Wq   = (const float*)d_in[3];
    const float* Wk   = (const float*)d_in[4];
    const float* Ve   = (const float*)d_in[5];

    float* out  = (float*)d_out;
    float* ctx  = out;
    float* attn = out + NB * HD;

    float* ws  = (float*)d_ws;
    float* wq_ = ws;                          // 32768 f
    float* sp  = ws + 32768;                  // 16*65536 f
    float* cp  = sp + 16 * (long)MM;          // 32*32*1024 f
    short* wkb = (short*)(cp + 32 * 32 * HE); // 1M bf16   (2 MB)
    short* encb = wkb + (long)HD * HE;        // 67.1M bf16 (128 MB)
    const size_t need = (size_t)((char*)(encb + (long)MM * HE) - (char*)d_ws);

    qproj_kernel<<<256, 256, 0, stream>>>(dh, Wq, wq_);
    if (ws_size >= need) {
        cvt_bf16_kernel<<<512, 256, 0, stream>>>(Wk, wkb, HD * HE / 8);
        cvt_bf16_kernel<<<2048, 256, 0, stream>>>(enc, encb, (int)((long)MM * HE / 8));
        score_bf16_kernel<<<4096, 256, 0, stream>>>(encb, wkb, wq_, Ve, sp);
        softmax_kernel<<<32, 256, 0, stream>>>(sp, mask, attn);
        ctx_partial_bf16_kernel<<<1024, 256, 0, stream>>>(encb, attn, cp);
    } else {
        score_f32_kernel<<<4096, 256, 0, stream>>>(enc, Wk, wq_, Ve, sp);
        softmax_kernel<<<32, 256, 0, stream>>>(sp, mask, attn);
        ctx_partial_f32_kernel<<<1024, 256, 0, stream>>>(enc, attn, cp);
    }
    ctx_reduce_kernel<<<128, 256, 0, stream>>>(cp, ctx);
}